// Round 1
// baseline (237.859 us; speedup 1.0000x reference)
//
#include <hip/hip_runtime.h>

#define W_ 160
#define H_ 128
#define C_ 32
#define D_ 48
#define HW_ (H_*W_)      // 20480
#define TX 16
#define TY 12
#define HPX 18           // halo tile x
#define HPY 14           // halo tile y
#define NHP (HPX*HPY)    // 252
#define VST 36           // padded LDS stride (floats) per halo pixel

__device__ __forceinline__ void inv4x4(const float* a, float* inv) {
    inv[0]  =  a[5]*a[10]*a[15] - a[5]*a[11]*a[14] - a[9]*a[6]*a[15] + a[9]*a[7]*a[14] + a[13]*a[6]*a[11] - a[13]*a[7]*a[10];
    inv[4]  = -a[4]*a[10]*a[15] + a[4]*a[11]*a[14] + a[8]*a[6]*a[15] - a[8]*a[7]*a[14] - a[12]*a[6]*a[11] + a[12]*a[7]*a[10];
    inv[8]  =  a[4]*a[9]*a[15]  - a[4]*a[11]*a[13] - a[8]*a[5]*a[15] + a[8]*a[7]*a[13] + a[12]*a[5]*a[11] - a[12]*a[7]*a[9];
    inv[12] = -a[4]*a[9]*a[14]  + a[4]*a[10]*a[13] + a[8]*a[5]*a[14] - a[8]*a[6]*a[13] - a[12]*a[5]*a[10] + a[12]*a[6]*a[9];
    inv[1]  = -a[1]*a[10]*a[15] + a[1]*a[11]*a[14] + a[9]*a[2]*a[15] - a[9]*a[3]*a[14] - a[13]*a[2]*a[11] + a[13]*a[3]*a[10];
    inv[5]  =  a[0]*a[10]*a[15] - a[0]*a[11]*a[14] - a[8]*a[2]*a[15] + a[8]*a[3]*a[14] + a[12]*a[2]*a[11] - a[12]*a[3]*a[10];
    inv[9]  = -a[0]*a[9]*a[15]  + a[0]*a[11]*a[13] + a[8]*a[1]*a[15] - a[8]*a[3]*a[13] - a[12]*a[1]*a[11] + a[12]*a[3]*a[9];
    inv[13] =  a[0]*a[9]*a[14]  - a[0]*a[10]*a[13] - a[8]*a[1]*a[14] + a[8]*a[2]*a[13] + a[12]*a[1]*a[10] - a[12]*a[2]*a[9];
    inv[2]  =  a[1]*a[6]*a[15]  - a[1]*a[7]*a[14]  - a[5]*a[2]*a[15] + a[5]*a[3]*a[14] + a[13]*a[2]*a[7]  - a[13]*a[3]*a[6];
    inv[6]  = -a[0]*a[6]*a[15]  + a[0]*a[7]*a[14]  + a[4]*a[2]*a[15] - a[4]*a[3]*a[14] - a[12]*a[2]*a[7]  + a[12]*a[3]*a[6];
    inv[10] =  a[0]*a[5]*a[15]  - a[0]*a[7]*a[13]  - a[4]*a[1]*a[15] + a[4]*a[3]*a[13] + a[12]*a[1]*a[7]  - a[12]*a[3]*a[5];
    inv[14] = -a[0]*a[5]*a[14]  + a[0]*a[6]*a[13]  + a[4]*a[1]*a[14] - a[4]*a[2]*a[13] - a[12]*a[1]*a[6]  + a[12]*a[2]*a[5];
    inv[3]  = -a[1]*a[6]*a[11]  + a[1]*a[7]*a[10]  + a[5]*a[2]*a[11] - a[5]*a[3]*a[10] - a[9]*a[2]*a[7]   + a[9]*a[3]*a[6];
    inv[7]  =  a[0]*a[6]*a[11]  - a[0]*a[7]*a[10]  - a[4]*a[2]*a[11] + a[4]*a[3]*a[10] + a[8]*a[2]*a[7]   - a[8]*a[3]*a[6];
    inv[11] = -a[0]*a[5]*a[11]  + a[0]*a[7]*a[9]   + a[4]*a[1]*a[11] - a[4]*a[3]*a[9]  - a[8]*a[1]*a[7]   + a[8]*a[3]*a[5];
    inv[15] =  a[0]*a[5]*a[10]  - a[0]*a[6]*a[9]   - a[4]*a[1]*a[10] + a[4]*a[2]*a[9]  + a[8]*a[1]*a[6]   - a[8]*a[2]*a[5];
    float det = a[0]*inv[0] + a[1]*inv[4] + a[2]*inv[8] + a[3]*inv[12];
    float id = 1.0f / det;
    for (int i = 0; i < 16; ++i) inv[i] *= id;
}

// Compute rot(3x3)+trans(3) for views 1..4: P = fuse(src) @ inv(fuse(ref))
__global__ __launch_bounds__(64) void kPrep(const float* __restrict__ proj, float* __restrict__ M) {
    if (threadIdx.x != 0 || blockIdx.x != 0) return;
    float F[5][16];
    for (int i = 0; i < 5; ++i) {
        const float* A = proj + i*32;      // pair[0]
        const float* R = A + 16;           // pair[1]
        for (int r = 0; r < 3; ++r)
            for (int k = 0; k < 4; ++k)
                F[i][r*4+k] = R[r*4]*A[k] + R[r*4+1]*A[4+k] + R[r*4+2]*A[8+k];
        for (int k = 0; k < 4; ++k) F[i][12+k] = A[12+k];
    }
    float inv[16];
    inv4x4(F[0], inv);
    for (int v = 1; v < 5; ++v) {
        float P[16];
        for (int r = 0; r < 4; ++r)
            for (int c = 0; c < 4; ++c) {
                float acc = 0.f;
                for (int k = 0; k < 4; ++k) acc += F[v][r*4+k]*inv[k*4+c];
                P[r*4+c] = acc;
            }
        float* o = M + (v-1)*12;
        o[0]=P[0]; o[1]=P[1]; o[2]=P[2];
        o[3]=P[4]; o[4]=P[5]; o[5]=P[6];
        o[6]=P[8]; o[7]=P[9]; o[8]=P[10];
        o[9]=P[3]; o[10]=P[7]; o[11]=P[11];
    }
}

// Transpose features (v,c,p) -> (v,p,c) channel-contiguous
__global__ __launch_bounds__(256) void kT(const float* __restrict__ f, float* __restrict__ ft) {
    __shared__ float t[64][33];
    const int v = blockIdx.y;
    const int p0 = blockIdx.x * 64;
    const int tid = threadIdx.x;
    const int pl = tid & 63;
    const int cb = (tid >> 6) * 8;
    #pragma unroll
    for (int k = 0; k < 8; ++k)
        t[pl][cb + k] = f[(v*C_ + cb + k)*HW_ + p0 + pl];
    __syncthreads();
    const int c2 = tid & 31;
    const int pb = tid >> 5;
    #pragma unroll
    for (int k = 0; k < 8; ++k) {
        const int pl2 = pb + k*8;
        ft[(size_t)(v*HW_ + p0 + pl2)*C_ + c2] = t[pl2][c2];
    }
}

// Main fused kernel: per (d, 16x12 tile): warp 4 views, variance in LDS, 3x3 spatial conv
// emitting 3 depth-tap partial planes Q[kd][d][p].
__global__ __launch_bounds__(256) void kA(const float* __restrict__ featT,
                                          const float* __restrict__ M,
                                          const float* __restrict__ dvals,
                                          const float* __restrict__ regw,
                                          float* __restrict__ Q) {
    __shared__ __align__(16) float Vt[NHP*VST];   // 36288 B
    __shared__ __align__(16) float Wl[27*32];     // 3456 B
    const int tid = threadIdx.x;
    // stage conv weights rearranged tap-major, channel-contiguous
    for (int t = tid; t < 864; t += 256) {
        const int tap = t >> 5, c = t & 31;
        Wl[t] = regw[c*27 + tap];
    }
    const int bx = blockIdx.x, by = blockIdx.y, d = blockIdx.z;
    const float dv = dvals[d];
    const int cg4 = (tid & 7) << 2;   // channel offset 0..28
    const int psub = tid >> 3;        // 0..31: pixel within pass

    #pragma unroll 1
    for (int pass = 0; pass < 8; ++pass) {
        const int pix = pass*32 + psub;
        if (pix >= NHP) continue;
        const int hx = pix % HPX;
        const int hy = pix / HPX;
        const int lx = bx*TX + hx - 1;
        const int ly = by*TY + hy - 1;
        float* vout = &Vt[pix*VST + cg4];
        if (lx < 0 || lx >= W_ || ly < 0 || ly >= H_) {
            vout[0] = 0.f; vout[1] = 0.f; vout[2] = 0.f; vout[3] = 0.f;
            continue;
        }
        const float4 f0 = *(const float4*)(featT + ((ly*W_ + lx) << 5) + cg4);
        float sx = f0.x, sy = f0.y, sz = f0.z, sw = f0.w;
        float qx = sx*sx, qy = sy*sy, qz = sz*sz, qw = sw*sw;
        const float xf = (float)lx, yf = (float)ly;
        #pragma unroll
        for (int v = 0; v < 4; ++v) {
            const float* mm = M + v*12;
            const float pxn = (mm[0]*xf + mm[1]*yf + mm[2])*dv + mm[9];
            const float pyn = (mm[3]*xf + mm[4]*yf + mm[5])*dv + mm[10];
            const float z   = (mm[6]*xf + mm[7]*yf + mm[8])*dv + mm[11];
            const float px = pxn / z;
            const float py = pyn / z;
            const float x0f = floorf(px), y0f = floorf(py);
            const float x1f = x0f + 1.f, y1f = y0f + 1.f;
            const float wx1 = px - x0f, wx0 = 1.f - wx1;
            const float wy1 = py - y0f, wy0 = 1.f - wy1;
            const float vx0 = (x0f >= 0.f && x0f <= (float)(W_-1)) ? 1.f : 0.f;
            const float vx1 = (x1f >= 0.f && x1f <= (float)(W_-1)) ? 1.f : 0.f;
            const float vy0 = (y0f >= 0.f && y0f <= (float)(H_-1)) ? 1.f : 0.f;
            const float vy1 = (y1f >= 0.f && y1f <= (float)(H_-1)) ? 1.f : 0.f;
            const int ix0 = (int)fminf(fmaxf(x0f, 0.f), (float)(W_-1));
            const int ix1 = (int)fminf(fmaxf(x1f, 0.f), (float)(W_-1));
            const int iy0 = (int)fminf(fmaxf(y0f, 0.f), (float)(H_-1));
            const int iy1 = (int)fminf(fmaxf(y1f, 0.f), (float)(H_-1));
            const float w00 = wx0*wy0*vx0*vy0;
            const float w10 = wx1*wy0*vx1*vy0;
            const float w01 = wx0*wy1*vx0*vy1;
            const float w11 = wx1*wy1*vx1*vy1;
            const float* vb = featT + (((v+1)*HW_) << 5) + cg4;
            const float4 f00 = *(const float4*)(vb + ((iy0*W_ + ix0) << 5));
            const float4 f10 = *(const float4*)(vb + ((iy0*W_ + ix1) << 5));
            const float4 f01 = *(const float4*)(vb + ((iy1*W_ + ix0) << 5));
            const float4 f11 = *(const float4*)(vb + ((iy1*W_ + ix1) << 5));
            const float gx = w00*f00.x + w10*f10.x + w01*f01.x + w11*f11.x;
            const float gy = w00*f00.y + w10*f10.y + w01*f01.y + w11*f11.y;
            const float gz = w00*f00.z + w10*f10.z + w01*f01.z + w11*f11.z;
            const float gw = w00*f00.w + w10*f10.w + w01*f01.w + w11*f11.w;
            sx += gx; qx += gx*gx;
            sy += gy; qy += gy*gy;
            sz += gz; qz += gz*gz;
            sw += gw; qw += gw*gw;
        }
        const float invN = 0.2f;
        const float ax = sx*invN, ay = sy*invN, az = sz*invN, aw = sw*invN;
        float4 o;
        o.x = qx*invN - ax*ax;
        o.y = qy*invN - ay*ay;
        o.z = qz*invN - az*az;
        o.w = qw*invN - aw*aw;
        *(float4*)vout = o;
    }
    __syncthreads();

    // spatial 3x3 conv over C for 3 depth taps
    if (tid < TX*TY) {
        const int x = tid & 15;
        const int y = tid >> 4;
        const int gy = by*TY + y;
        if (gy < H_) {
            float c0 = 0.f, c1 = 0.f, c2 = 0.f;
            #pragma unroll
            for (int jy = 0; jy < 3; ++jy) {
                #pragma unroll
                for (int jx = 0; jx < 3; ++jx) {
                    const float* vr = &Vt[((y+jy)*HPX + (x+jx))*VST];
                    const int tap = jy*3 + jx;
                    const float* wp0 = &Wl[tap*32];
                    const float* wp1 = &Wl[(9+tap)*32];
                    const float* wp2 = &Wl[(18+tap)*32];
                    #pragma unroll
                    for (int g = 0; g < 8; ++g) {
                        const float4 vv = *(const float4*)(vr + g*4);
                        const float4 a0 = *(const float4*)(wp0 + g*4);
                        const float4 a1 = *(const float4*)(wp1 + g*4);
                        const float4 a2 = *(const float4*)(wp2 + g*4);
                        c0 += vv.x*a0.x + vv.y*a0.y + vv.z*a0.z + vv.w*a0.w;
                        c1 += vv.x*a1.x + vv.y*a1.y + vv.z*a1.z + vv.w*a1.w;
                        c2 += vv.x*a2.x + vv.y*a2.y + vv.z*a2.z + vv.w*a2.w;
                    }
                }
            }
            const int p = gy*W_ + bx*TX + x;
            Q[(size_t)(0*D_ + d)*HW_ + p] = c0;
            Q[(size_t)(1*D_ + d)*HW_ + p] = c1;
            Q[(size_t)(2*D_ + d)*HW_ + p] = c2;
        }
    }
}

// Finalize: combine depth taps, softmax over D, depth + confidence
__global__ __launch_bounds__(256) void kB(const float* __restrict__ Q,
                                          const float* __restrict__ dvals,
                                          float* __restrict__ out) {
    const int p = blockIdx.x*256 + threadIdx.x;
    const float* Q0 = Q;
    const float* Q1 = Q + (size_t)D_*HW_;
    const float* Q2 = Q + (size_t)2*D_*HW_;
    float pr[D_];
    #pragma unroll
    for (int d = 0; d < D_; ++d) {
        float c = Q1[d*HW_ + p];
        if (d > 0)     c += Q0[(d-1)*HW_ + p];
        if (d < D_-1)  c += Q2[(d+1)*HW_ + p];
        pr[d] = c;
    }
    float m = pr[0];
    #pragma unroll
    for (int d = 1; d < D_; ++d) m = fmaxf(m, pr[d]);
    float s = 0.f;
    #pragma unroll
    for (int d = 0; d < D_; ++d) { const float e = __expf(pr[d] - m); pr[d] = e; s += e; }
    const float is = 1.f / s;
    float depth = 0.f, fidx = 0.f;
    #pragma unroll
    for (int d = 0; d < D_; ++d) {
        const float pp = pr[d] * is;
        pr[d] = pp;
        depth += pp * dvals[d];
        fidx  += pp * (float)d;
    }
    int di = (int)fidx;
    di = di < 0 ? 0 : (di > D_-1 ? D_-1 : di);
    float conf = 0.f;
    #pragma unroll
    for (int d = 0; d < D_; ++d)
        conf += ((d >= di-1) && (d <= di+2)) ? pr[d] : 0.f;
    out[p] = depth;
    out[HW_ + p] = conf;
}

extern "C" void kernel_launch(void* const* d_in, const int* in_sizes, int n_in,
                              void* d_out, int out_size, void* d_ws, size_t ws_size,
                              hipStream_t stream) {
    const float* features = (const float*)d_in[0];
    const float* proj     = (const float*)d_in[1];
    const float* dvals    = (const float*)d_in[2];
    const float* regw     = (const float*)d_in[3];
    float* out = (float*)d_out;

    float* featT = (float*)d_ws;                         // 5*20480*32 floats = 13.1 MB
    float* M     = featT + (size_t)5*HW_*C_;             // 48 floats (+pad)
    float* Q     = M + 64;                               // 3*48*20480 floats = 11.8 MB

    kPrep<<<1, 64, 0, stream>>>(proj, M);
    kT<<<dim3(HW_/64, 5), 256, 0, stream>>>(features, featT);
    kA<<<dim3(W_/TX, (H_ + TY - 1)/TY, D_), 256, 0, stream>>>(featT, M, dvals, regw, Q);
    kB<<<HW_/256, 256, 0, stream>>>(Q, dvals, out);
}

// Round 3
// 185.599 us; speedup vs baseline: 1.2816x; 1.2816x over previous
//
#include <hip/hip_runtime.h>

#define W_ 160
#define H_ 128
#define C_ 32
#define D_ 48
#define HW_ (H_*W_)      // 20480
#define TX 16
#define TY 16
#define HPX 18
#define HPY 18
#define NHP (HPX*HPY)    // 324
#define NHPP 336         // padded to 21 MFMA tiles of 16

typedef _Float16 h8 __attribute__((ext_vector_type(8)));
typedef _Float16 h4 __attribute__((ext_vector_type(4)));
typedef __fp16 fp16x2 __attribute__((ext_vector_type(2)));
typedef float f4 __attribute__((ext_vector_type(4)));

__device__ __forceinline__ _Float16 u2h(unsigned int u) {
    union { unsigned short s; _Float16 h; } x; x.s = (unsigned short)u; return x.h;
}
__device__ __forceinline__ unsigned int pkh2(float a, float b) {
    union { fp16x2 h; unsigned int u; } x;
    x.h = __builtin_amdgcn_cvt_pkrtz(a, b);
    return x.u;
}

__device__ __forceinline__ void inv4x4(const float* a, float* inv) {
    inv[0]  =  a[5]*a[10]*a[15] - a[5]*a[11]*a[14] - a[9]*a[6]*a[15] + a[9]*a[7]*a[14] + a[13]*a[6]*a[11] - a[13]*a[7]*a[10];
    inv[4]  = -a[4]*a[10]*a[15] + a[4]*a[11]*a[14] + a[8]*a[6]*a[15] - a[8]*a[7]*a[14] - a[12]*a[6]*a[11] + a[12]*a[7]*a[10];
    inv[8]  =  a[4]*a[9]*a[15]  - a[4]*a[11]*a[13] - a[8]*a[5]*a[15] + a[8]*a[7]*a[13] + a[12]*a[5]*a[11] - a[12]*a[7]*a[9];
    inv[12] = -a[4]*a[9]*a[14]  + a[4]*a[10]*a[13] + a[8]*a[5]*a[14] - a[8]*a[6]*a[13] - a[12]*a[5]*a[10] + a[12]*a[6]*a[9];
    inv[1]  = -a[1]*a[10]*a[15] + a[1]*a[11]*a[14] + a[9]*a[2]*a[15] - a[9]*a[3]*a[14] - a[13]*a[2]*a[11] + a[13]*a[3]*a[10];
    inv[5]  =  a[0]*a[10]*a[15] - a[0]*a[11]*a[14] - a[8]*a[2]*a[15] + a[8]*a[3]*a[14] + a[12]*a[2]*a[11] - a[12]*a[3]*a[10];
    inv[9]  = -a[0]*a[9]*a[15]  + a[0]*a[11]*a[13] + a[8]*a[1]*a[15] - a[8]*a[3]*a[13] - a[12]*a[1]*a[11] + a[12]*a[3]*a[9];
    inv[13] =  a[0]*a[9]*a[14]  - a[0]*a[10]*a[13] - a[8]*a[1]*a[14] + a[8]*a[2]*a[13] + a[12]*a[1]*a[10] - a[12]*a[2]*a[9];
    inv[2]  =  a[1]*a[6]*a[15]  - a[1]*a[7]*a[14]  - a[5]*a[2]*a[15] + a[5]*a[3]*a[14] + a[13]*a[2]*a[7]  - a[13]*a[3]*a[6];
    inv[6]  = -a[0]*a[6]*a[15]  + a[0]*a[7]*a[14]  + a[4]*a[2]*a[15] - a[4]*a[3]*a[14] - a[12]*a[2]*a[7]  + a[12]*a[3]*a[6];
    inv[10] =  a[0]*a[5]*a[15]  - a[0]*a[7]*a[13]  - a[4]*a[1]*a[15] + a[4]*a[3]*a[13] + a[12]*a[1]*a[7]  - a[12]*a[3]*a[5];
    inv[14] = -a[0]*a[5]*a[14]  + a[0]*a[6]*a[13]  + a[4]*a[1]*a[14] - a[4]*a[2]*a[13] - a[12]*a[1]*a[6]  + a[12]*a[2]*a[5];
    inv[3]  = -a[1]*a[6]*a[11]  + a[1]*a[7]*a[10]  + a[5]*a[2]*a[11] - a[5]*a[3]*a[10] - a[9]*a[2]*a[7]   + a[9]*a[3]*a[6];
    inv[7]  =  a[0]*a[6]*a[11]  - a[0]*a[7]*a[10]  - a[4]*a[2]*a[11] + a[4]*a[3]*a[10] + a[8]*a[2]*a[7]   - a[8]*a[3]*a[6];
    inv[11] = -a[0]*a[5]*a[11]  + a[0]*a[7]*a[9]   + a[4]*a[1]*a[11] - a[4]*a[3]*a[9]  - a[8]*a[1]*a[7]   + a[8]*a[3]*a[5];
    inv[15] =  a[0]*a[5]*a[10]  - a[0]*a[6]*a[9]   - a[4]*a[1]*a[10] + a[4]*a[2]*a[9]  + a[8]*a[1]*a[6]   - a[8]*a[2]*a[5];
    float det = a[0]*inv[0] + a[1]*inv[4] + a[2]*inv[8] + a[3]*inv[12];
    float id = 1.0f / det;
    for (int i = 0; i < 16; ++i) inv[i] *= id;
}

// rot(3x3)+trans(3) for views 1..4: P = fuse(src) @ inv(fuse(ref))
__global__ __launch_bounds__(64) void kPrep(const float* __restrict__ proj, float* __restrict__ M) {
    if (threadIdx.x != 0 || blockIdx.x != 0) return;
    float F[5][16];
    for (int i = 0; i < 5; ++i) {
        const float* A = proj + i*32;
        const float* R = A + 16;
        for (int r = 0; r < 3; ++r)
            for (int k = 0; k < 4; ++k)
                F[i][r*4+k] = R[r*4]*A[k] + R[r*4+1]*A[4+k] + R[r*4+2]*A[8+k];
        for (int k = 0; k < 4; ++k) F[i][12+k] = A[12+k];
    }
    float inv[16];
    inv4x4(F[0], inv);
    for (int v = 1; v < 5; ++v) {
        float P[16];
        for (int r = 0; r < 4; ++r)
            for (int c = 0; c < 4; ++c) {
                float acc = 0.f;
                for (int k = 0; k < 4; ++k) acc += F[v][r*4+k]*inv[k*4+c];
                P[r*4+c] = acc;
            }
        float* o = M + (v-1)*12;
        o[0]=P[0]; o[1]=P[1]; o[2]=P[2];
        o[3]=P[4]; o[4]=P[5]; o[5]=P[6];
        o[6]=P[8]; o[7]=P[9]; o[8]=P[10];
        o[9]=P[3]; o[10]=P[7]; o[11]=P[11];
    }
}

// Depth-invariant rot*(x,y,1) per pixel per view -> RX[v][p] = float4
__global__ __launch_bounds__(256) void kR(const float* __restrict__ M, float* __restrict__ RX) {
    const int v = blockIdx.y;
    const int p = blockIdx.x*256 + threadIdx.x;
    const float* m = M + v*12;
    const float x = (float)(p % W_), y = (float)(p / W_);
    float4 o;
    o.x = m[0]*x + m[1]*y + m[2];
    o.y = m[3]*x + m[4]*y + m[5];
    o.z = m[6]*x + m[7]*y + m[8];
    o.w = 0.f;
    ((float4*)RX)[(size_t)v*HW_ + p] = o;
}

// Transpose features (v,c,p) f32 -> (v,p,c) f16 channel-contiguous
__global__ __launch_bounds__(256) void kT(const float* __restrict__ f, _Float16* __restrict__ ft) {
    __shared__ float t[64][33];
    const int v = blockIdx.y;
    const int p0 = blockIdx.x * 64;
    const int tid = threadIdx.x;
    const int pl = tid & 63;
    const int cb = (tid >> 6) * 8;
    #pragma unroll
    for (int k = 0; k < 8; ++k)
        t[pl][cb + k] = f[(size_t)(v*C_ + cb + k)*HW_ + p0 + pl];
    __syncthreads();
    const int px = tid >> 2;
    const int c0 = (tid & 3) * 8;
    h8 o;
    #pragma unroll
    for (int k = 0; k < 8; ++k) o[k] = (_Float16)t[px][c0 + k];
    *(h8*)&ft[((size_t)(v*HW_ + p0 + px) << 5) + c0] = o;
}

// Fused: project(once/px) -> gather+lerp+variance (f16 pk) -> per-tap channel
// dot via MFMA -> spatial shifted-sum -> Q[kd][d][p]
__global__ __launch_bounds__(256) void kA(const _Float16* __restrict__ featH,
                                          const float* __restrict__ RX,
                                          const float* __restrict__ M,
                                          const float* __restrict__ dvals,
                                          const float* __restrict__ regw,
                                          float* __restrict__ Q) {
    __shared__ __align__(16) _Float16 VT[NHPP*32];    // 21504 B variance, MFMA-A layout
    __shared__ __align__(16) unsigned int SMA[6048];  // 24192 B: PRJ (phase1/2) ∪ DL (phase3/4)
    __shared__ float Msh[48];
    uint4* PRJ4 = (uint4*)SMA;
    _Float16* DL = (_Float16*)SMA;

    const int tid = threadIdx.x;
    const int bx = blockIdx.x, by = blockIdx.y, d = blockIdx.z;
    const int lane = tid & 63;
    const float dv = dvals[d];

    if (tid < 48) Msh[tid] = M[tid];

    // B fragments (weights, taps as cols: col = sp*4 + kd, sp=ky*3+kx) in regs
    h8 bf0, bf1, bf2;
    {
        const int n = lane & 15;
        const int kb = (lane >> 4) * 8;
        #pragma unroll
        for (int j = 0; j < 8; ++j) {
            const int ch = kb + j;
            int col0 = n, col1 = 16 + n, col2 = 32 + n;
            int sp, kd;
            sp = col0 >> 2; kd = col0 & 3;
            bf0[j] = (_Float16)((kd < 3 && sp < 9) ? regw[ch*27 + kd*9 + sp] : 0.f);
            sp = col1 >> 2; kd = col1 & 3;
            bf1[j] = (_Float16)((kd < 3 && sp < 9) ? regw[ch*27 + kd*9 + sp] : 0.f);
            sp = col2 >> 2; kd = col2 & 3;
            bf2[j] = (_Float16)((kd < 3 && sp < 9) ? regw[ch*27 + kd*9 + sp] : 0.f);
        }
    }
    __syncthreads();

    // ---- Phase 1: projection once per halo pixel ----
    #pragma unroll 1
    for (int pp = 0; pp < 2; ++pp) {
        const int px = pp*256 + tid;
        if (px >= NHP) continue;
        const int hx = px % HPX;
        const int hy = px / HPX;
        const int lx = bx*TX + hx - 1;
        const int ly = by*TY + hy - 1;
        if (lx < 0 || lx >= W_ || ly < 0 || ly >= H_) {
            const uint4 z = make_uint4(0,0,0,0);
            PRJ4[px*4+0] = z; PRJ4[px*4+1] = z; PRJ4[px*4+2] = z; PRJ4[px*4+3] = z;
        } else {
            const int rp = ly*W_ + lx;
            #pragma unroll
            for (int v = 0; v < 4; ++v) {
                const float4 a = ((const float4*)RX)[(size_t)v*HW_ + rp];
                const float tx = Msh[v*12+9], ty = Msh[v*12+10], tz = Msh[v*12+11];
                const float z  = a.z*dv + tz;
                const float rz = 1.0f / z;
                const float pxf = (a.x*dv + tx)*rz;
                const float pyf = (a.y*dv + ty)*rz;
                const float x0f = floorf(pxf), y0f = floorf(pyf);
                const float wx1 = pxf - x0f, wy1 = pyf - y0f;
                const float vx0 = (x0f >= 0.f && x0f <= (float)(W_-1)) ? 1.f : 0.f;
                const float vx1 = (x0f >= -1.f && x0f <= (float)(W_-2)) ? 1.f : 0.f;
                const float vy0 = (y0f >= 0.f && y0f <= (float)(H_-1)) ? 1.f : 0.f;
                const float vy1 = (y0f >= -1.f && y0f <= (float)(H_-2)) ? 1.f : 0.f;
                const int ix0 = (int)fminf(fmaxf(x0f,      0.f), (float)(W_-1));
                const int ix1 = (int)fminf(fmaxf(x0f + 1.f,0.f), (float)(W_-1));
                const int iy0 = (int)fminf(fmaxf(y0f,      0.f), (float)(H_-1));
                const int iy1 = (int)fminf(fmaxf(y0f + 1.f,0.f), (float)(H_-1));
                const float wx0v = (1.f - wx1)*vx0, wx1v = wx1*vx1;
                const float wy0v = (1.f - wy1)*vy0, wy1v = wy1*vy1;
                uint4 r;
                r.x = (unsigned)ix0 | ((unsigned)ix1 << 16);
                r.y = (unsigned)(iy0*W_) | ((unsigned)(iy1*W_) << 16);
                r.z = pkh2(wx0v*wy0v, wx1v*wy0v);
                r.w = pkh2(wx0v*wy1v, wx1v*wy1v);
                PRJ4[px*4+v] = r;
            }
        }
    }
    __syncthreads();

    // ---- Phase 2: gather + lerp + variance (f16 packed), 4 threads/px ----
    const h8 hz = {(_Float16)0,(_Float16)0,(_Float16)0,(_Float16)0,
                   (_Float16)0,(_Float16)0,(_Float16)0,(_Float16)0};
    const h8* F = (const h8*)featH;
    #pragma unroll 1
    for (int pass = 0; pass < 6; ++pass) {
        const int idx = pass*256 + tid;
        if (idx >= NHPP*4) continue;
        const int px = idx >> 2, u = idx & 3;
        h8 var = hz;
        if (px < NHP) {
            const int hx = px % HPX;
            const int hy = px / HPX;
            const int lx = bx*TX + hx - 1;
            const int ly = by*TY + hy - 1;
            h8 s = hz, q = hz;
            if (lx >= 0 && lx < W_ && ly >= 0 && ly < H_) {
                const h8 f = F[(size_t)(ly*W_ + lx)*4 + u];
                s = f; q = f*f;
            }
            #pragma unroll
            for (int v = 0; v < 4; ++v) {
                const uint4 r = PRJ4[px*4+v];
                const int x0 = r.x & 0xffff, x1 = r.x >> 16;
                const int y0 = r.y & 0xffff, y1 = r.y >> 16;
                const h8* Fv = F + (size_t)(v+1)*HW_*4;
                const h8 f00 = Fv[(y0+x0)*4 + u];
                const h8 f10 = Fv[(y0+x1)*4 + u];
                const h8 f01 = Fv[(y1+x0)*4 + u];
                const h8 f11 = Fv[(y1+x1)*4 + u];
                const _Float16 w00 = u2h(r.z), w10 = u2h(r.z >> 16);
                const _Float16 w01 = u2h(r.w), w11 = u2h(r.w >> 16);
                const h8 g = f00*w00 + f10*w10 + f01*w01 + f11*w11;
                s += g;
                q += g*g;
            }
            const _Float16 c5 = (_Float16)0.2f;
            const h8 s5 = s * c5;
            var = q * c5 - s5*s5;
        }
        *(h8*)&VT[px*32 + u*8] = var;
    }
    __syncthreads();

    // ---- Phase 3: per-tap channel dot via MFMA ----
    {
        const int wv = tid >> 6;
        const f4 fz = {0.f, 0.f, 0.f, 0.f};
        #pragma unroll 1
        for (int tile = wv; tile < NHPP/16; tile += 4) {
            const h8 a = *(const h8*)&VT[(tile*16 + (lane & 15))*32 + (lane >> 4)*8];
            const f4 d0 = __builtin_amdgcn_mfma_f32_16x16x32_f16(a, bf0, fz, 0, 0, 0);
            const f4 d1 = __builtin_amdgcn_mfma_f32_16x16x32_f16(a, bf1, fz, 0, 0, 0);
            const f4 d2 = __builtin_amdgcn_mfma_f32_16x16x32_f16(a, bf2, fz, 0, 0, 0);
            const int col = lane & 15;
            const int rbase = tile*16 + (lane >> 4)*4;
            #pragma unroll
            for (int r = 0; r < 4; ++r) {
                _Float16* dr = &DL[(rbase + r)*36];
                dr[col]      = (_Float16)d0[r];
                dr[16 + col] = (_Float16)d1[r];
                if (col < 4) dr[32 + col] = (_Float16)d2[r];
            }
        }
    }
    __syncthreads();

    // ---- Phase 4: 27-term spatial shifted sum -> Q[kd][d][p] ----
    {
        const int x = tid & 15;
        const int y = tid >> 4;
        float c0 = 0.f, c1 = 0.f, c2 = 0.f;
        #pragma unroll
        for (int jy = 0; jy < 3; ++jy) {
            #pragma unroll
            for (int jx = 0; jx < 3; ++jx) {
                const int hp = (y + jy)*HPX + (x + jx);
                const int sp = jy*3 + jx;
                const h4 t = *(const h4*)&DL[hp*36 + sp*4];
                c0 += (float)t.x;
                c1 += (float)t.y;
                c2 += (float)t.z;
            }
        }
        const int p = (by*TY + y)*W_ + bx*TX + x;
        Q[(size_t)(0*D_ + d)*HW_ + p] = c0;
        Q[(size_t)(1*D_ + d)*HW_ + p] = c1;
        Q[(size_t)(2*D_ + d)*HW_ + p] = c2;
    }
}

// Finalize: combine depth taps, softmax over D, depth + confidence
__global__ __launch_bounds__(256) void kB(const float* __restrict__ Q,
                                          const float* __restrict__ dvals,
                                          float* __restrict__ out) {
    const int p = blockIdx.x*256 + threadIdx.x;
    const float* Q0 = Q;
    const float* Q1 = Q + (size_t)D_*HW_;
    const float* Q2 = Q + (size_t)2*D_*HW_;
    float pr[D_];
    #pragma unroll
    for (int d = 0; d < D_; ++d) {
        float c = Q1[d*HW_ + p];
        if (d > 0)     c += Q0[(d-1)*HW_ + p];
        if (d < D_-1)  c += Q2[(d+1)*HW_ + p];
        pr[d] = c;
    }
    float m = pr[0];
    #pragma unroll
    for (int d = 1; d < D_; ++d) m = fmaxf(m, pr[d]);
    float s = 0.f;
    #pragma unroll
    for (int d = 0; d < D_; ++d) { const float e = __expf(pr[d] - m); pr[d] = e; s += e; }
    const float is = 1.f / s;
    float depth = 0.f, fidx = 0.f;
    #pragma unroll
    for (int d = 0; d < D_; ++d) {
        const float pp = pr[d] * is;
        pr[d] = pp;
        depth += pp * dvals[d];
        fidx  += pp * (float)d;
    }
    int di = (int)fidx;
    di = di < 0 ? 0 : (di > D_-1 ? D_-1 : di);
    float conf = 0.f;
    #pragma unroll
    for (int d = 0; d < D_; ++d)
        conf += ((d >= di-1) && (d <= di+2)) ? pr[d] : 0.f;
    out[p] = depth;
    out[HW_ + p] = conf;
}

extern "C" void kernel_launch(void* const* d_in, const int* in_sizes, int n_in,
                              void* d_out, int out_size, void* d_ws, size_t ws_size,
                              hipStream_t stream) {
    const float* features = (const float*)d_in[0];
    const float* proj     = (const float*)d_in[1];
    const float* dvals    = (const float*)d_in[2];
    const float* regw     = (const float*)d_in[3];
    float* out = (float*)d_out;

    _Float16* featH = (_Float16*)d_ws;                       // 5*HW*32 f16 = 6.55 MB
    float* RX = (float*)(featH + (size_t)5*HW_*C_);          // 4*HW*4 f32 = 5.24 MB
    float* M  = RX + (size_t)4*HW_*4;                        // 48 floats (+pad)
    float* Q  = M + 64;                                      // 3*48*HW f32 = 11.8 MB

    kPrep<<<1, 64, 0, stream>>>(proj, M);
    kR<<<dim3(HW_/256, 4), 256, 0, stream>>>(M, RX);
    kT<<<dim3(HW_/64, 5), 256, 0, stream>>>(features, featH);
    kA<<<dim3(W_/TX, H_/TY, D_), 256, 0, stream>>>(featH, RX, M, dvals, regw, Q);
    kB<<<HW_/256, 256, 0, stream>>>(Q, dvals, out);
}

// Round 4
// 154.672 us; speedup vs baseline: 1.5378x; 1.1999x over previous
//
#include <hip/hip_runtime.h>

#define W_ 160
#define H_ 128
#define C_ 32
#define D_ 48
#define HW_ (H_*W_)      // 20480
#define TX 16
#define TY 16
#define HPX 18
#define HPY 18
#define NHP (HPX*HPY)    // 324
#define NHPP 336         // padded to 21 MFMA tiles of 16
#define DST 28           // DL stride in halfs (27 live taps kd*9+sp, +1 pad)

typedef _Float16 h8 __attribute__((ext_vector_type(8)));
typedef __fp16 fp16x2 __attribute__((ext_vector_type(2)));
typedef float f4 __attribute__((ext_vector_type(4)));

__device__ __forceinline__ _Float16 u2h(unsigned int u) {
    union { unsigned short s; _Float16 h; } x; x.s = (unsigned short)u; return x.h;
}
__device__ __forceinline__ unsigned int pkh2(float a, float b) {
    union { fp16x2 h; unsigned int u; } x;
    x.h = __builtin_amdgcn_cvt_pkrtz(a, b);
    return x.u;
}

__device__ __forceinline__ void inv4x4(const float* a, float* inv) {
    inv[0]  =  a[5]*a[10]*a[15] - a[5]*a[11]*a[14] - a[9]*a[6]*a[15] + a[9]*a[7]*a[14] + a[13]*a[6]*a[11] - a[13]*a[7]*a[10];
    inv[4]  = -a[4]*a[10]*a[15] + a[4]*a[11]*a[14] + a[8]*a[6]*a[15] - a[8]*a[7]*a[14] - a[12]*a[6]*a[11] + a[12]*a[7]*a[10];
    inv[8]  =  a[4]*a[9]*a[15]  - a[4]*a[11]*a[13] - a[8]*a[5]*a[15] + a[8]*a[7]*a[13] + a[12]*a[5]*a[11] - a[12]*a[7]*a[9];
    inv[12] = -a[4]*a[9]*a[14]  + a[4]*a[10]*a[13] + a[8]*a[5]*a[14] - a[8]*a[6]*a[13] - a[12]*a[5]*a[10] + a[12]*a[6]*a[9];
    inv[1]  = -a[1]*a[10]*a[15] + a[1]*a[11]*a[14] + a[9]*a[2]*a[15] - a[9]*a[3]*a[14] - a[13]*a[2]*a[11] + a[13]*a[3]*a[10];
    inv[5]  =  a[0]*a[10]*a[15] - a[0]*a[11]*a[14] - a[8]*a[2]*a[15] + a[8]*a[3]*a[14] + a[12]*a[2]*a[11] - a[12]*a[3]*a[10];
    inv[9]  = -a[0]*a[9]*a[15]  + a[0]*a[11]*a[13] + a[8]*a[1]*a[15] - a[8]*a[3]*a[13] - a[12]*a[1]*a[11] + a[12]*a[3]*a[9];
    inv[13] =  a[0]*a[9]*a[14]  - a[0]*a[10]*a[13] - a[8]*a[1]*a[14] + a[8]*a[2]*a[13] + a[12]*a[1]*a[10] - a[12]*a[2]*a[9];
    inv[2]  =  a[1]*a[6]*a[15]  - a[1]*a[7]*a[14]  - a[5]*a[2]*a[15] + a[5]*a[3]*a[14] + a[13]*a[2]*a[7]  - a[13]*a[3]*a[6];
    inv[6]  = -a[0]*a[6]*a[15]  + a[0]*a[7]*a[14]  + a[4]*a[2]*a[15] - a[4]*a[3]*a[14] - a[12]*a[2]*a[7]  + a[12]*a[3]*a[6];
    inv[10] =  a[0]*a[5]*a[15]  - a[0]*a[7]*a[13]  - a[4]*a[1]*a[15] + a[4]*a[3]*a[13] + a[12]*a[1]*a[7]  - a[12]*a[3]*a[5];
    inv[14] = -a[0]*a[5]*a[14]  + a[0]*a[6]*a[13]  + a[4]*a[1]*a[14] - a[4]*a[2]*a[13] - a[12]*a[1]*a[6]  + a[12]*a[2]*a[5];
    inv[3]  = -a[1]*a[6]*a[11]  + a[1]*a[7]*a[10]  + a[5]*a[2]*a[11] - a[5]*a[3]*a[10] - a[9]*a[2]*a[7]   + a[9]*a[3]*a[6];
    inv[7]  =  a[0]*a[6]*a[11]  - a[0]*a[7]*a[10]  - a[4]*a[2]*a[11] + a[4]*a[3]*a[10] + a[8]*a[2]*a[7]   - a[8]*a[3]*a[6];
    inv[11] = -a[0]*a[5]*a[11]  + a[0]*a[7]*a[9]   + a[4]*a[1]*a[11] - a[4]*a[3]*a[9]  - a[8]*a[1]*a[7]   + a[8]*a[3]*a[5];
    inv[15] =  a[0]*a[5]*a[10]  - a[0]*a[6]*a[9]   - a[4]*a[1]*a[10] + a[4]*a[2]*a[9]  + a[8]*a[1]*a[6]   - a[8]*a[2]*a[5];
    float det = a[0]*inv[0] + a[1]*inv[4] + a[2]*inv[8] + a[3]*inv[12];
    float id = 1.0f / det;
    for (int i = 0; i < 16; ++i) inv[i] *= id;
}

__device__ __forceinline__ void fuseProj(const float* proj, int i, float* F) {
    const float* A = proj + i*32;   // pair[0]
    const float* R = A + 16;        // pair[1]
    for (int r = 0; r < 3; ++r)
        for (int k = 0; k < 4; ++k)
            F[r*4+k] = R[r*4]*A[k] + R[r*4+1]*A[4+k] + R[r*4+2]*A[8+k];
    for (int k = 0; k < 4; ++k) F[12+k] = A[12+k];
}

// Fused setup: bx<320 -> feature transpose (f32 (v,c,p) -> f16 (v,p,c));
// bx>=320 -> per-pixel depth-invariant rot*(x,y,1) (RX), M computed inline;
// block (320, v) also publishes M[v] (rot+trans) for kA.
__global__ __launch_bounds__(256) void kS(const float* __restrict__ f,
                                          const float* __restrict__ proj,
                                          _Float16* __restrict__ ft,
                                          float* __restrict__ RX,
                                          float* __restrict__ M) {
    __shared__ float t[64][33];
    const int bx = blockIdx.x, v = blockIdx.y;
    const int tid = threadIdx.x;
    if (bx < 320) {
        const int p0 = bx * 64;
        const int pl = tid & 63;
        const int cb = (tid >> 6) * 8;
        #pragma unroll
        for (int k = 0; k < 8; ++k)
            t[pl][cb + k] = f[(size_t)(v*C_ + cb + k)*HW_ + p0 + pl];
        __syncthreads();
        const int px = tid >> 2;
        const int c0 = (tid & 3) * 8;
        h8 o;
        #pragma unroll
        for (int k = 0; k < 8; ++k) o[k] = (_Float16)t[px][c0 + k];
        *(h8*)&ft[((size_t)(v*HW_ + p0 + px) << 5) + c0] = o;
    } else {
        if (v >= 4) return;
        float F0[16], Fv[16], inv[16], P[12];
        fuseProj(proj, 0, F0);
        fuseProj(proj, v + 1, Fv);
        inv4x4(F0, inv);
        #pragma unroll
        for (int r = 0; r < 3; ++r)
            #pragma unroll
            for (int c = 0; c < 4; ++c) {
                float acc = 0.f;
                #pragma unroll
                for (int k = 0; k < 4; ++k) acc += Fv[r*4+k]*inv[k*4+c];
                P[r*4+c] = acc;
            }
        const int p = (bx - 320)*256 + tid;
        const float x = (float)(p % W_), y = (float)(p / W_);
        float4 o;
        o.x = P[0]*x + P[1]*y + P[2];
        o.y = P[4]*x + P[5]*y + P[6];
        o.z = P[8]*x + P[9]*y + P[10];
        o.w = 0.f;
        ((float4*)RX)[(size_t)v*HW_ + p] = o;
        if (bx == 320 && tid == 0) {
            float* om = M + v*12;
            om[0]=P[0]; om[1]=P[1]; om[2]=P[2];
            om[3]=P[4]; om[4]=P[5]; om[5]=P[6];
            om[6]=P[8]; om[7]=P[9]; om[8]=P[10];
            om[9]=P[3]; om[10]=P[7]; om[11]=P[11];
        }
    }
}

// Fused main: project(once/px, SoA LDS) -> gather+lerp+variance (f16 pk) ->
// per-tap channel dot via 2 MFMAs (kd-major cols) -> spatial shifted sum -> Q
__global__ __launch_bounds__(256) void kA(const _Float16* __restrict__ featH,
                                          const float* __restrict__ RX,
                                          const float* __restrict__ M,
                                          const float* __restrict__ dvals,
                                          const float* __restrict__ regw,
                                          float* __restrict__ Q) {
    __shared__ __align__(16) _Float16 VT[NHPP*32];     // 21504 B, MFMA-A layout
    __shared__ __align__(16) unsigned int SMA[4704];   // 18816 B: PRJ SoA (ph1/2) U DL (ph3/4)
    __shared__ float Tsh[12];
    unsigned int* PI  = SMA;              // [4][NHP] packed u8 x0,x1,y0,y1
    unsigned int* PWA = SMA + 4*NHP;      // [4][NHP] f16x2 w00,w10
    unsigned int* PWB = SMA + 8*NHP;      // [4][NHP] f16x2 w01,w11
    _Float16* DL = (_Float16*)SMA;        // [NHPP][DST]

    const int tid = threadIdx.x;
    const int bx = blockIdx.x, by = blockIdx.y, d = blockIdx.z;
    const int lane = tid & 63;
    const float dv = dvals[d];

    if (tid < 12) Tsh[tid] = M[(tid/3)*12 + 9 + (tid % 3)];

    // B fragments: col = kd*9 + sp (kd-major) -> regw[ch*27 + col], 27 live cols
    h8 bf0, bf1;
    {
        const int n = lane & 15;
        const int kb = (lane >> 4) * 8;
        #pragma unroll
        for (int j = 0; j < 8; ++j) {
            const int ch = kb + j;
            bf0[j] = (_Float16)regw[ch*27 + n];
            bf1[j] = (_Float16)((n < 11) ? regw[ch*27 + 16 + n] : 0.f);
        }
    }
    __syncthreads();

    // ---- Phase 1: projection once per halo pixel (SoA writes, conflict-free) ----
    #pragma unroll 1
    for (int pp = 0; pp < 2; ++pp) {
        const int px = pp*256 + tid;
        if (px >= NHP) continue;
        const int hx = px % HPX;
        const int hy = px / HPX;
        const int lx = bx*TX + hx - 1;
        const int ly = by*TY + hy - 1;
        if (lx < 0 || lx >= W_ || ly < 0 || ly >= H_) {
            #pragma unroll
            for (int v = 0; v < 4; ++v) {
                PI[v*NHP+px] = 0u; PWA[v*NHP+px] = 0u; PWB[v*NHP+px] = 0u;
            }
        } else {
            const int rp = ly*W_ + lx;
            #pragma unroll
            for (int v = 0; v < 4; ++v) {
                const float4 a = ((const float4*)RX)[(size_t)v*HW_ + rp];
                const float z  = a.z*dv + Tsh[v*3+2];
                const float rz = 1.0f / z;
                const float pxf = (a.x*dv + Tsh[v*3+0])*rz;
                const float pyf = (a.y*dv + Tsh[v*3+1])*rz;
                const float x0f = floorf(pxf), y0f = floorf(pyf);
                const float wx1 = pxf - x0f, wy1 = pyf - y0f;
                const float vx0 = (x0f >= 0.f && x0f <= (float)(W_-1)) ? 1.f : 0.f;
                const float vx1 = (x0f >= -1.f && x0f <= (float)(W_-2)) ? 1.f : 0.f;
                const float vy0 = (y0f >= 0.f && y0f <= (float)(H_-1)) ? 1.f : 0.f;
                const float vy1 = (y0f >= -1.f && y0f <= (float)(H_-2)) ? 1.f : 0.f;
                const int ix0 = (int)fminf(fmaxf(x0f,      0.f), (float)(W_-1));
                const int ix1 = (int)fminf(fmaxf(x0f + 1.f,0.f), (float)(W_-1));
                const int iy0 = (int)fminf(fmaxf(y0f,      0.f), (float)(H_-1));
                const int iy1 = (int)fminf(fmaxf(y0f + 1.f,0.f), (float)(H_-1));
                const float wx0v = (1.f - wx1)*vx0, wx1v = wx1*vx1;
                const float wy0v = (1.f - wy1)*vy0, wy1v = wy1*vy1;
                PI [v*NHP+px] = (unsigned)ix0 | ((unsigned)ix1 << 8)
                              | ((unsigned)iy0 << 16) | ((unsigned)iy1 << 24);
                PWA[v*NHP+px] = pkh2(wx0v*wy0v, wx1v*wy0v);
                PWB[v*NHP+px] = pkh2(wx0v*wy1v, wx1v*wy1v);
            }
        }
    }
    __syncthreads();

    // ---- Phase 2: gather + lerp + variance (f16 packed), 4 threads/px ----
    const h8 hz = {(_Float16)0,(_Float16)0,(_Float16)0,(_Float16)0,
                   (_Float16)0,(_Float16)0,(_Float16)0,(_Float16)0};
    const h8* F = (const h8*)featH;
    #pragma unroll 1
    for (int pass = 0; pass < 6; ++pass) {
        const int idx = pass*256 + tid;
        if (idx >= NHPP*4) continue;
        const int px = idx >> 2, u = idx & 3;
        h8 var = hz;
        if (px < NHP) {
            const int hx = px % HPX;
            const int hy = px / HPX;
            const int lx = bx*TX + hx - 1;
            const int ly = by*TY + hy - 1;
            h8 s = hz, q = hz;
            if (lx >= 0 && lx < W_ && ly >= 0 && ly < H_) {
                const h8 f = F[(size_t)(ly*W_ + lx)*4 + u];
                s = f; q = f*f;
            }
            #pragma unroll
            for (int v = 0; v < 4; ++v) {
                const unsigned ri = PI [v*NHP+px];
                const unsigned wa = PWA[v*NHP+px];
                const unsigned wb = PWB[v*NHP+px];
                const int x0 = ri & 0xff, x1 = (ri >> 8) & 0xff;
                const int y0W = ((ri >> 16) & 0xff) * W_;
                const int y1W = (ri >> 24) * W_;
                const h8* Fv = F + (size_t)(v+1)*HW_*4;
                const h8 f00 = Fv[(y0W+x0)*4 + u];
                const h8 f10 = Fv[(y0W+x1)*4 + u];
                const h8 f01 = Fv[(y1W+x0)*4 + u];
                const h8 f11 = Fv[(y1W+x1)*4 + u];
                const _Float16 w00 = u2h(wa), w10 = u2h(wa >> 16);
                const _Float16 w01 = u2h(wb), w11 = u2h(wb >> 16);
                const h8 g = f00*w00 + f10*w10 + f01*w01 + f11*w11;
                s += g;
                q += g*g;
            }
            const _Float16 c5 = (_Float16)0.2f;
            const h8 s5 = s * c5;
            var = q * c5 - s5*s5;
        }
        *(h8*)&VT[px*32 + u*8] = var;
    }
    __syncthreads();

    // ---- Phase 3: per-tap channel dot via 2 MFMAs per 16-pixel tile ----
    {
        const int wv = tid >> 6;
        const int n = lane & 15;
        const int grp = lane >> 4;
        const f4 fz = {0.f, 0.f, 0.f, 0.f};
        #pragma unroll 1
        for (int tile = wv; tile < NHPP/16; tile += 4) {
            const h8 a = *(const h8*)&VT[(tile*16 + n)*32 + grp*8];
            const f4 d0 = __builtin_amdgcn_mfma_f32_16x16x32_f16(a, bf0, fz, 0, 0, 0);
            const f4 d1 = __builtin_amdgcn_mfma_f32_16x16x32_f16(a, bf1, fz, 0, 0, 0);
            const int rbase = tile*16 + grp*4;
            #pragma unroll
            for (int r = 0; r < 4; ++r) {
                _Float16* dr = &DL[(rbase + r)*DST];
                dr[n] = (_Float16)d0[r];
                if (n < 11) dr[16 + n] = (_Float16)d1[r];
            }
        }
    }
    __syncthreads();

    // ---- Phase 4: 27-term spatial shifted sum -> Q[kd][d][p] ----
    {
        const int x = tid & 15;
        const int y = tid >> 4;
        float c0 = 0.f, c1 = 0.f, c2 = 0.f;
        #pragma unroll
        for (int jy = 0; jy < 3; ++jy) {
            #pragma unroll
            for (int jx = 0; jx < 3; ++jx) {
                const int hp = (y + jy)*HPX + (x + jx);
                const int sp = jy*3 + jx;
                const _Float16* dr = &DL[hp*DST];
                c0 += (float)dr[sp];
                c1 += (float)dr[9 + sp];
                c2 += (float)dr[18 + sp];
            }
        }
        const int p = (by*TY + y)*W_ + bx*TX + x;
        Q[(size_t)(0*D_ + d)*HW_ + p] = c0;
        Q[(size_t)(1*D_ + d)*HW_ + p] = c1;
        Q[(size_t)(2*D_ + d)*HW_ + p] = c2;
    }
}

// Finalize: combine depth taps, softmax over D, depth + confidence
__global__ __launch_bounds__(128) void kB(const float* __restrict__ Q,
                                          const float* __restrict__ dvals,
                                          float* __restrict__ out) {
    const int p = blockIdx.x*128 + threadIdx.x;
    const float* Q0 = Q;
    const float* Q1 = Q + (size_t)D_*HW_;
    const float* Q2 = Q + (size_t)2*D_*HW_;
    float pr[D_];
    #pragma unroll
    for (int d = 0; d < D_; ++d) {
        float c = Q1[d*HW_ + p];
        if (d > 0)     c += Q0[(d-1)*HW_ + p];
        if (d < D_-1)  c += Q2[(d+1)*HW_ + p];
        pr[d] = c;
    }
    float m = pr[0];
    #pragma unroll
    for (int d = 1; d < D_; ++d) m = fmaxf(m, pr[d]);
    float s = 0.f;
    #pragma unroll
    for (int d = 0; d < D_; ++d) { const float e = __expf(pr[d] - m); pr[d] = e; s += e; }
    const float is = 1.f / s;
    float depth = 0.f, fidx = 0.f;
    #pragma unroll
    for (int d = 0; d < D_; ++d) {
        const float pp = pr[d] * is;
        pr[d] = pp;
        depth += pp * dvals[d];
        fidx  += pp * (float)d;
    }
    int di = (int)fidx;
    di = di < 0 ? 0 : (di > D_-1 ? D_-1 : di);
    float conf = 0.f;
    #pragma unroll
    for (int d = 0; d < D_; ++d)
        conf += ((d >= di-1) && (d <= di+2)) ? pr[d] : 0.f;
    out[p] = depth;
    out[HW_ + p] = conf;
}

extern "C" void kernel_launch(void* const* d_in, const int* in_sizes, int n_in,
                              void* d_out, int out_size, void* d_ws, size_t ws_size,
                              hipStream_t stream) {
    const float* features = (const float*)d_in[0];
    const float* proj     = (const float*)d_in[1];
    const float* dvals    = (const float*)d_in[2];
    const float* regw     = (const float*)d_in[3];
    float* out = (float*)d_out;

    _Float16* featH = (_Float16*)d_ws;                       // 5*HW*32 f16 = 6.55 MB
    float* RX = (float*)(featH + (size_t)5*HW_*C_);          // 4*HW*4 f32 = 5.24 MB
    float* M  = RX + (size_t)4*HW_*4;                        // 48 floats (+pad)
    float* Q  = M + 64;                                      // 3*48*HW f32 = 11.8 MB

    kS<<<dim3(400, 5), 256, 0, stream>>>(features, proj, featH, RX, M);
    kA<<<dim3(W_/TX, H_/TY, D_), 256, 0, stream>>>(featH, RX, M, dvals, regw, Q);
    kB<<<HW_/128, 128, 0, stream>>>(Q, dvals, out);
}